// Round 8
// baseline (175.205 us; speedup 1.0000x reference)
//
#include <hip/hip_runtime.h>
#include <cstddef>

// CAM module, algebraically restructured:
//   X = concat(rgb,hsv,lab) : [B=4, 192, N=65536] (f32)
//   G[b] = X X^T (192x192), s[b] = row sums        (K1, fp16 MFMA, gl_lds DMA staging)
//   energy = (Wq G Wk^T + bq sk^T + sq bk^T + N bq bk^T)/8 ; att = softmax_d
//   M = att Wv (emitted as swizzled fp16) ; c0 = att bv   (K2, f32)
//   out = M X + c0                                  (K3, fp16 MFMA, memory-bound)
//
// Round-7 lesson (occupancy quantum, m69): waves/CU cap = 32 only at VGPR<=64.
// R7's DMA-staged K1 compiled to exactly 64 VGPR but ran on a 1-block/CU grid.
// This round keeps that kernel IDENTICAL and doubles the grid (512 blocks,
// 512 cols each): 2 co-resident 12-wave blocks/CU so one block's MFMA covers
// the other's vmcnt(0)+barrier drain (K3's proven mechanism).

#define NPIX 65536

typedef _Float16 half8_t __attribute__((ext_vector_type(8)));
typedef float f32x4_t __attribute__((ext_vector_type(4)));

// ---------------- K0: zero a float range ----------------
__global__ void k0_zero(float* __restrict__ p, int n) {
  int i = blockIdx.x * 256 + threadIdx.x;
  if (i < n) p[i] = 0.0f;
}

// ---------------- K1: Gram + row sums ----------------
// grid (128, 4) = 512 blocks (2/CU), block 768 (12 waves as 3x4).
// 512 cols/block, 16 chunks of 32 f32 cols. LDS: 2 x [192][32] f32 (24 KB each).
// Staging: per chunk each wave issues 2 global_load_lds dwordx4 (1 KB each);
// lds[row][g] (16B granule) holds X[row][4*(g ^ (row&7))] (swizzle baked into
// per-lane SOURCE address; LDS dest linear  - m173 pattern).
// Wave (wi,wj) in 3x4: A-tiles wi*4+a (a<4), B-tiles wj*3+j (j<3); acc[4][3].
// mode: 2 = direct partials (128 slots/batch), 1 = pairwise-atomic partials
// (64 slots, pre-zeroed; two-way fp adds commute bitwise -> deterministic),
// 0 = atomicAdd into zeroed G/S.
__global__ __launch_bounds__(768) void k1_gram(
    const float* __restrict__ rgb, const float* __restrict__ hsv, const float* __restrict__ lab,
    float* __restrict__ G, float* __restrict__ S, float* __restrict__ part, int mode) {
  __shared__ alignas(16) float ldsb[2][6144];  // 2 x 24 KB

  const int t = threadIdx.x;
  const int lane = t & 63;
  const int w = t >> 6;            // 0..11
  const int wi = w >> 2;           // 0..2: A row-group (4 tiles = 64 rows)
  const int wj = w & 3;            // 0..3: B col-group (3 tiles = 48 rows)
  const int b = blockIdx.y;
  const int bx = blockIdx.x;       // 0..127
  const int n0 = bx * 512;

  // staging source addresses (2 DMA rounds per chunk):
  // round r: wave stages LDS f32 [(w*2+r)*256, +256) = rows (w*2+r)*8 .. +7.
  // lane l -> row = (w*2+r)*8 + (l>>3), granule g = l&7; source granule
  // sg = g ^ (row&7)  (XOR swizzle baked into source address).
  const float* gsrc[2];
#pragma unroll
  for (int r = 0; r < 2; ++r) {
    int row = (w * 2 + r) * 8 + (lane >> 3);
    int rs = row >> 6;  // uniform per (w,r): 8-row groups never straddle 64
    const float* sp = (rs == 0) ? rgb : (rs == 1) ? hsv : lab;
    int sg = (lane & 7) ^ (row & 7);
    gsrc[r] = sp + (size_t)(b * 64 + (row & 63)) * NPIX + n0 + 4 * sg;
  }

  f32x4_t acc[4][3];
  const f32x4_t zero4 = {0.0f, 0.0f, 0.0f, 0.0f};
#pragma unroll
  for (int a = 0; a < 4; ++a)
#pragma unroll
    for (int j = 0; j < 3; ++j) acc[a][j] = zero4;

  float srow = 0.0f;                 // row-sum partial: row t>>2, quarter t&3
  const int sr_r = t >> 2;
  const int sr_q = t & 3;

  const int l15 = lane & 15;
  const int gk = 2 * (lane >> 4);    // fragment granule base (k = 8*(lane>>4) f32)

  auto stage = [&](int cc) {
    const int par = cc & 1;
#pragma unroll
    for (int r = 0; r < 2; ++r) {
      __builtin_amdgcn_global_load_lds(
          (const __attribute__((address_space(1))) void*)(gsrc[r] + cc * 32),
          (__attribute__((address_space(3))) void*)(&ldsb[par][(w * 2 + r) * 256]),
          16, 0, 0);
    }
  };

  auto compute = [&](int cc) {
    const int par = cc & 1;
    half8_t fB16[3];
#pragma unroll
    for (int j = 0; j < 3; ++j) {
      int rB = wj * 48 + j * 16 + l15;
      f32x4_t lo = *(const f32x4_t*)(&ldsb[par][rB * 32 + ((gk ^ (rB & 7)) << 2)]);
      f32x4_t hi = *(const f32x4_t*)(&ldsb[par][rB * 32 + (((gk + 1) ^ (rB & 7)) << 2)]);
      half8_t f;
      f[0] = (_Float16)lo[0]; f[1] = (_Float16)lo[1];
      f[2] = (_Float16)lo[2]; f[3] = (_Float16)lo[3];
      f[4] = (_Float16)hi[0]; f[5] = (_Float16)hi[1];
      f[6] = (_Float16)hi[2]; f[7] = (_Float16)hi[3];
      fB16[j] = f;
    }
#pragma unroll
    for (int a = 0; a < 4; ++a) {
      int rA = wi * 64 + a * 16 + l15;
      f32x4_t lo = *(const f32x4_t*)(&ldsb[par][rA * 32 + ((gk ^ (rA & 7)) << 2)]);
      f32x4_t hi = *(const f32x4_t*)(&ldsb[par][rA * 32 + (((gk + 1) ^ (rA & 7)) << 2)]);
      half8_t fa;
      fa[0] = (_Float16)lo[0]; fa[1] = (_Float16)lo[1];
      fa[2] = (_Float16)lo[2]; fa[3] = (_Float16)lo[3];
      fa[4] = (_Float16)hi[0]; fa[5] = (_Float16)hi[1];
      fa[6] = (_Float16)hi[2]; fa[7] = (_Float16)hi[3];
#pragma unroll
      for (int j = 0; j < 3; ++j)
        acc[a][j] = __builtin_amdgcn_mfma_f32_16x16x32_f16(fa, fB16[j], acc[a][j], 0, 0, 0);
    }
    // row sums: this thread's 8 f32 of (row sr_r, granules 2q, 2q+1)
    {
      f32x4_t s0 = *(const f32x4_t*)(&ldsb[par][sr_r * 32 + (((2 * sr_q) ^ (sr_r & 7)) << 2)]);
      f32x4_t s1 = *(const f32x4_t*)(&ldsb[par][sr_r * 32 + (((2 * sr_q + 1) ^ (sr_r & 7)) << 2)]);
      srow += (s0[0] + s0[1]) + (s0[2] + s0[3]) + (s1[0] + s1[1]) + (s1[2] + s1[3]);
    }
  };

  stage(0);
  asm volatile("s_waitcnt vmcnt(0) lgkmcnt(0)" ::: "memory");
  __builtin_amdgcn_s_barrier();
  for (int cc = 0; cc < 16; ++cc) {
    if (cc + 1 < 16) stage(cc + 1);   // DMA for next buffer, in flight under compute
    compute(cc);
    asm volatile("s_waitcnt vmcnt(0) lgkmcnt(0)" ::: "memory");
    __builtin_amdgcn_s_barrier();
  }

  // ---- flush Gram ----
  if (mode == 2) {
    float* pb = part + (size_t)(b * 128 + bx) * 37056;
#pragma unroll
    for (int a = 0; a < 4; ++a)
#pragma unroll
      for (int j = 0; j < 3; ++j) {
        int tt = (wi * 4 + a) * 12 + (wj * 3 + j);
        *(f32x4_t*)(pb + tt * 256 + lane * 4) = acc[a][j];
      }
  } else if (mode == 1) {
    float* pb = part + (size_t)(b * 64 + (bx >> 1)) * 37056;
#pragma unroll
    for (int a = 0; a < 4; ++a)
#pragma unroll
      for (int j = 0; j < 3; ++j) {
        int tt = (wi * 4 + a) * 12 + (wj * 3 + j);
#pragma unroll
        for (int r = 0; r < 4; ++r)
          atomicAdd(pb + tt * 256 + lane * 4 + r, acc[a][j][r]);
      }
  } else {
    float* Gb = G + b * 36864;
#pragma unroll
    for (int a = 0; a < 4; ++a)
#pragma unroll
      for (int j = 0; j < 3; ++j) {
#pragma unroll
        for (int r = 0; r < 4; ++r) {
          int gr = (wi * 4 + a) * 16 + ((lane >> 4) << 2) + r;
          int gc = (wj * 3 + j) * 16 + (lane & 15);
          atomicAdd(Gb + gr * 192 + gc, acc[a][j][r]);
        }
      }
  }

  // ---- row sums: reduce 4 quarters per row via LDS (buf0 is free) ----
  float* slds = &ldsb[0][0];
  __syncthreads();
  slds[t] = srow;
  __syncthreads();
  if (t < 192) {
    float v = (slds[4 * t] + slds[4 * t + 1]) + (slds[4 * t + 2] + slds[4 * t + 3]);
    if (mode == 2)
      part[(size_t)(b * 128 + bx) * 37056 + 36864 + t] = v;
    else if (mode == 1)
      atomicAdd(part + (size_t)(b * 64 + (bx >> 1)) * 37056 + 36864 + t, v);
    else
      atomicAdd(S + b * 192 + t, v);
  }
}

// ---------------- K1.5: deterministic reduce of P partials/batch ----------------
__global__ void k1r_reduce(const float* __restrict__ part, float* __restrict__ G,
                           float* __restrict__ S, int P) {
  int idx = blockIdx.x * 256 + threadIdx.x;
  if (idx >= 4 * 37056) return;
  int b = idx / 37056;
  int flat = idx % 37056;
  const float* base = part + (size_t)b * P * 37056 + flat;
  float v0 = 0.f, v1 = 0.f, v2 = 0.f, v3 = 0.f;
  for (int q = 0; q < P; q += 4) {
    v0 += base[(size_t)(q + 0) * 37056];
    v1 += base[(size_t)(q + 1) * 37056];
    v2 += base[(size_t)(q + 2) * 37056];
    v3 += base[(size_t)(q + 3) * 37056];
  }
  float v = (v0 + v1) + (v2 + v3);
  if (flat < 36864) {
    int tt = flat >> 8;
    int I = tt / 12, J = tt % 12;
    int r = flat & 255;
    int lane = r >> 2, rg = r & 3;
    int row = I * 16 + ((lane >> 4) << 2) + rg;
    int col = J * 16 + (lane & 15);
    G[b * 36864 + row * 192 + col] = v;
  } else {
    S[b * 192 + (flat - 36864)] = v;
  }
}

// ---------------- K2: energy -> softmax -> M(fp16 swizzled), c0 ----------------
__global__ __launch_bounds__(256) void k2_small(
    const float* __restrict__ G, const float* __restrict__ S,
    const float* __restrict__ Wq, const float* __restrict__ bq,
    const float* __restrict__ Wk, const float* __restrict__ bk,
    const float* __restrict__ Wv, const float* __restrict__ bv,
    _Float16* __restrict__ Mh, float* __restrict__ c0w) {
  const int b = blockIdx.y;
  const int cbase = blockIdx.x * 8;
  const int t = threadIdx.x;
  __shared__ float T1[192 * 9];
  __shared__ float el[64 * 8];
  __shared__ float sq[8];
  __shared__ float sk[64];
  const float* Gb = G + b * 36864;
  const float* Sb = S + b * 192;

  if (t < 8) {
    float a = 0.f;
    const float* wq = Wq + (cbase + t) * 192;
    for (int i = 0; i < 192; ++i) a = fmaf(wq[i], Sb[i], a);
    sq[t] = a;
  } else if (t < 72) {
    int d = t - 8;
    float a = 0.f;
    const float* wk = Wk + d * 192;
    for (int j = 0; j < 192; ++j) a = fmaf(wk[j], Sb[j], a);
    sk[d] = a;
  }
  for (int e = t; e < 1536; e += 256) {
    int j = e % 192, cp = e / 192;
    const float* wq = Wq + (cbase + cp) * 192;
    float a = 0.f;
    for (int i = 0; i < 192; ++i) a = fmaf(wq[i], Gb[i * 192 + j], a);
    T1[j * 9 + cp] = a;
  }
  __syncthreads();
  for (int e = t; e < 512; e += 256) {
    int cp = e & 7, d = e >> 3;
    const float* wk = Wk + d * 192;
    float a = 0.f;
    for (int j = 0; j < 192; ++j) a = fmaf(T1[j * 9 + cp], wk[j], a);
    float bqc = bq[cbase + cp], bkd = bk[d];
    a += bqc * sk[d] + bkd * sq[cp] + 65536.0f * bqc * bkd;
    el[d * 8 + cp] = a * 0.125f;
  }
  __syncthreads();
  if (t < 8) {
    float mx = -3.0e38f;
    for (int d = 0; d < 64; ++d) mx = fmaxf(mx, el[d * 8 + t]);
    float sum = 0.f;
    for (int d = 0; d < 64; ++d) {
      float pv = expf(el[d * 8 + t] - mx);
      el[d * 8 + t] = pv;
      sum += pv;
    }
    float inv = 1.0f / sum;
    for (int d = 0; d < 64; ++d) el[d * 8 + t] *= inv;
  }
  __syncthreads();
  // M rows in fp16, swizzled exactly as K3's lds_m image: idx = c*192 + (i ^ ((c&7)<<3))
  for (int e = t; e < 1536; e += 256) {
    int i = e % 192, cp = e / 192;
    int c = cbase + cp;
    float a = 0.f;
    for (int d = 0; d < 64; ++d) a = fmaf(el[d * 8 + cp], Wv[d * 192 + i], a);
    Mh[(size_t)b * 12288 + c * 192 + (i ^ ((c & 7) << 3))] = (_Float16)a;
  }
  if (t < 8) {
    float a = 0.f;
    for (int d = 0; d < 64; ++d) a = fmaf(el[d * 8 + t], bv[d], a);
    c0w[b * 64 + cbase + t] = a;
  }
}

// ---------------- K3: out = M X + c0 (fp16 MFMA) ----------------
// grid (256, 4), block 256 (4 waves). Block: C[64 x 256n]; wave w: n-span w*64.
// X chunk [32 i][256 n] staged transposed into lds_x[n][32] fp16, swizzle i^=(n&3)<<3.
// M staged once (linear copy of pre-swizzled fp16 image). acc[4][4] = 64 VGPR.
__global__ __launch_bounds__(256, 3) void k3_out(
    const float* __restrict__ rgb, const float* __restrict__ hsv, const float* __restrict__ lab,
    const _Float16* __restrict__ Mh, const float* __restrict__ c0w, float* __restrict__ out) {
  __shared__ alignas(16) _Float16 lds_m[12288];
  __shared__ alignas(16) _Float16 lds_x[8192];
  __shared__ float c0l[64];
  const int t = threadIdx.x;
  const int lane = t & 63;
  const int w = t >> 6;
  const int b = blockIdx.y;
  const int nblk = blockIdx.x * 256;

  {  // stage M (24576 B) as 16B copies + c0
    const float4* msrc = (const float4*)(Mh + (size_t)b * 12288);
    float4* mdst = (float4*)lds_m;
#pragma unroll
    for (int k = 0; k < 6; ++k) mdst[t + 256 * k] = msrc[t + 256 * k];
    if (t < 64) c0l[t] = c0w[b * 64 + t];
  }

  const int xi = t & 31;   // i within chunk
  const int ng = t >> 5;   // 0..7: n-group of 32
  const float* srcs[3] = {rgb, hsv, lab};

  f32x4_t acc[4][4];
  const f32x4_t zero4 = {0.0f, 0.0f, 0.0f, 0.0f};
#pragma unroll
  for (int i = 0; i < 4; ++i)
#pragma unroll
    for (int j = 0; j < 4; ++j) acc[i][j] = zero4;

  float4 xr[8];
  auto xload = [&](int kc) {
    int ig = kc * 32 + xi;
    const float* p = srcs[ig >> 6] + (size_t)(b * 64 + (ig & 63)) * NPIX + nblk + ng * 32;
#pragma unroll
    for (int f = 0; f < 8; ++f) xr[f] = *(const float4*)(p + f * 4);
  };
  auto xwrite = [&]() {
#pragma unroll
    for (int f = 0; f < 8; ++f) {
      int n = ng * 32 + f * 4;
      lds_x[(n + 0) * 32 + (xi ^ 0)]  = (_Float16)xr[f].x;
      lds_x[(n + 1) * 32 + (xi ^ 8)]  = (_Float16)xr[f].y;
      lds_x[(n + 2) * 32 + (xi ^ 16)] = (_Float16)xr[f].z;
      lds_x[(n + 3) * 32 + (xi ^ 24)] = (_Float16)xr[f].w;
    }
  };

  const int g = lane >> 4;     // 0..3
  const int l15 = lane & 15;

  xload(0);
  for (int kc = 0; kc < 6; ++kc) {
    xwrite();
    __syncthreads();
    if (kc + 1 < 6) xload(kc + 1);
    half8_t fx[4], fm[4];
#pragma unroll
    for (int nt = 0; nt < 4; ++nt) {
      int n = w * 64 + nt * 16 + l15;
      fx[nt] = *(const half8_t*)(lds_x + n * 32 + ((8 * g) ^ ((n & 3) << 3)));
    }
#pragma unroll
    for (int ct = 0; ct < 4; ++ct) {
      int c = ct * 16 + l15;
      fm[ct] = *(const half8_t*)(lds_m + c * 192 + ((kc * 32 + 8 * g) ^ ((c & 7) << 3)));
    }
#pragma unroll
    for (int nt = 0; nt < 4; ++nt)
#pragma unroll
      for (int ct = 0; ct < 4; ++ct)
        acc[nt][ct] = __builtin_amdgcn_mfma_f32_16x16x32_f16(fx[nt], fm[ct], acc[nt][ct], 0, 0, 0);
    __syncthreads();
  }

  // epilogue: C-row (n) = 4*g + r from first operand, C-col (c) = l15 from second
#pragma unroll
  for (int ct = 0; ct < 4; ++ct) {
    int c = ct * 16 + l15;
    float c0v = c0l[c];
#pragma unroll
    for (int nt = 0; nt < 4; ++nt) {
      int n = nblk + w * 64 + nt * 16 + 4 * g;
      float4 o;
      o.x = acc[nt][ct][0] + c0v;
      o.y = acc[nt][ct][1] + c0v;
      o.z = acc[nt][ct][2] + c0v;
      o.w = acc[nt][ct][3] + c0v;
      *(float4*)(out + (size_t)(b * 64 + c) * NPIX + n) = o;
    }
  }
}

extern "C" void kernel_launch(void* const* d_in, const int* in_sizes, int n_in,
                              void* d_out, int out_size, void* d_ws, size_t ws_size,
                              hipStream_t stream) {
  const float* rgb = (const float*)d_in[0];
  const float* hsv = (const float*)d_in[1];
  const float* lab = (const float*)d_in[2];
  const float* Wq = (const float*)d_in[3];
  const float* bq = (const float*)d_in[4];
  const float* Wk = (const float*)d_in[5];
  const float* bk = (const float*)d_in[6];
  const float* Wv = (const float*)d_in[7];
  const float* bv = (const float*)d_in[8];
  float* out = (float*)d_out;
  float* ws = (float*)d_ws;

  float* G = ws;                            // 147456 f32
  float* S = ws + 147456;                   // 768
  _Float16* Mh = (_Float16*)(ws + 148224);  // 49152 halves = 24576 f32 slots
  float* c0w = ws + 172800;                 // 256
  float* part = ws + 173056;                // up to 512*37056 f32
  const size_t need2 = (size_t)(173056 + 512 * 37056) * 4;  // 75.9 MB (128 slots x 4 b)
  const size_t need1 = (size_t)(173056 + 256 * 37056) * 4;  // 38.6 MB (64 slots x 4 b)
  const int mode = ws_size >= need2 ? 2 : (ws_size >= need1 ? 1 : 0);

  if (mode == 1)
    k0_zero<<<dim3(37056), dim3(256), 0, stream>>>(part, 256 * 37056);
  else if (mode == 0)
    k0_zero<<<dim3(579), dim3(256), 0, stream>>>(ws, 148224);  // zero G + S

  k1_gram<<<dim3(128, 4), dim3(768), 0, stream>>>(rgb, hsv, lab, G, S, part, mode);
  if (mode)
    k1r_reduce<<<dim3(579), dim3(256), 0, stream>>>(part, G, S, mode == 2 ? 128 : 64);
  k2_small<<<dim3(8, 4), dim3(256), 0, stream>>>(G, S, Wq, bq, Wk, bk, Wv, bv, Mh, c0w);
  k3_out<<<dim3(256, 4), dim3(256), 0, stream>>>(rgb, hsv, lab, Mh, c0w, out);
}

// Round 9
// 166.954 us; speedup vs baseline: 1.0494x; 1.0494x over previous
//
#include <hip/hip_runtime.h>
#include <cstddef>

// CAM module, algebraically restructured:
//   X = concat(rgb,hsv,lab) : [B=4, 192, N=65536] (f32)
//   G[b] = X X^T (192x192), s[b] = row sums        (K1, fp16 MFMA)
//   energy = (Wq G Wk^T + bq sk^T + sq bk^T + N bq bk^T)/8 ; att = softmax_d
//   M = att Wv (emitted as swizzled fp16) ; c0 = att bv   (K2, f32)
//   out = M X + c0                                  (K3, fp16 MFMA, memory-bound)
//
// Occupancy model (corrected, R8): gfx950 reports VGPR and AGPR separately;
// occupancy is set by the UNIFIED total (m98). All 12-wave K1s carried
// ~64 arch + 48 acc = 112 total -> 4 waves/SIMD -> 16-wave cap -> one resident
// 12-wave block, so the per-chunk barrier drain was never covered by TLP.
// This round: 512-thr blocks (8 waves), total regs ~117 <= 128 -> 2 blocks/CU.
// Staging: T14 async split (loads issued after raw s_barrier, lgkmcnt-only
// drain; loads in flight across the barrier), fp16 LDS (12KB/chunk) with
// 2-way-free swizzle granule g -> g ^ ((row>>1)&3).

#define NPIX 65536

typedef _Float16 half4_t __attribute__((ext_vector_type(4)));
typedef _Float16 half8_t __attribute__((ext_vector_type(8)));
typedef float f32x4_t __attribute__((ext_vector_type(4)));

// ---------------- K0: zero a float range ----------------
__global__ void k0_zero(float* __restrict__ p, int n) {
  int i = blockIdx.x * 256 + threadIdx.x;
  if (i < n) p[i] = 0.0f;
}

// ---------------- K1: Gram + row sums ----------------
// grid (128, 4) = 512 blocks (2/CU), block 512 (8 waves as 2x4).
// 512 cols/block, 16 chunks of 32 cols. LDS: 2 x [192][32] fp16 (12 KB each).
// Per chunk/thread: 12 f32 loaded (3 float4), cvt to fp16, 3 ds_write_b64.
// Wave (wi,wj): A-tiles wi*6+a (a<6), B-tiles wj*3+j (j<3); acc[6][3] = 72.
// mode: 2 = direct partials (128 slots/batch) else 0 = atomicAdd zeroed G/S.
__global__ __launch_bounds__(512) void k1_gram(
    const float* __restrict__ rgb, const float* __restrict__ hsv, const float* __restrict__ lab,
    float* __restrict__ G, float* __restrict__ S, float* __restrict__ part, int mode) {
  __shared__ alignas(16) _Float16 ldsb[2][6144];  // 2 x 12 KB
  float* slds = (float*)&ldsb[0][0];              // rowsum scratch (6 KB, in buf0)

  const int t = threadIdx.x;
  const int lane = t & 63;
  const int w = t >> 6;            // 0..7
  const int wi = w >> 2;           // 0..1: A group (6 tiles = 96 rows)
  const int wj = w & 3;            // 0..3: B group (3 tiles = 48 rows)
  const int b = blockIdx.y;
  const int bx = blockIdx.x;       // 0..127
  const int n0 = bx * 512;

  // staging map: round p in {0,1,2} = source p; row = p*64 + rr, 4 cols at 4*c8.
  const int rr = t >> 3;           // 0..63
  const int c8 = t & 7;            // 0..7
  const float* gp0 = rgb + (size_t)(b * 64 + rr) * NPIX + n0 + 4 * c8;
  const float* gp1 = hsv + (size_t)(b * 64 + rr) * NPIX + n0 + 4 * c8;
  const float* gp2 = lab + (size_t)(b * 64 + rr) * NPIX + n0 + 4 * c8;

  // LDS half-index for write: row*32 + ((c8>>1)^swz)*8 + (c8&1)*4, swz=(rr>>1)&3
  const int swz = (rr >> 1) & 3;
  const int wbase = ((c8 >> 1) ^ swz) * 8 + (c8 & 1) * 4;
  const int wof0 = (0 * 64 + rr) * 32 + wbase;
  const int wof1 = (1 * 64 + rr) * 32 + wbase;
  const int wof2 = (2 * 64 + rr) * 32 + wbase;

  f32x4_t acc[6][3];
  const f32x4_t zero4 = {0.0f, 0.0f, 0.0f, 0.0f};
#pragma unroll
  for (int a = 0; a < 6; ++a)
#pragma unroll
    for (int j = 0; j < 3; ++j) acc[a][j] = zero4;
  float sr0 = 0.f, sr1 = 0.f, sr2 = 0.f;

  float4 R0, R1, R2;
  auto loadR = [&](int cc) {
    R0 = *(const float4*)(gp0 + cc * 32);
    R1 = *(const float4*)(gp1 + cc * 32);
    R2 = *(const float4*)(gp2 + cc * 32);
  };
  auto writeL = [&](int par) {
    _Float16* buf = &ldsb[par][0];
    half4_t h;
    sr0 += (R0.x + R0.y) + (R0.z + R0.w);
    h.x = (_Float16)R0.x; h.y = (_Float16)R0.y; h.z = (_Float16)R0.z; h.w = (_Float16)R0.w;
    *(half4_t*)(buf + wof0) = h;
    sr1 += (R1.x + R1.y) + (R1.z + R1.w);
    h.x = (_Float16)R1.x; h.y = (_Float16)R1.y; h.z = (_Float16)R1.z; h.w = (_Float16)R1.w;
    *(half4_t*)(buf + wof1) = h;
    sr2 += (R2.x + R2.y) + (R2.z + R2.w);
    h.x = (_Float16)R2.x; h.y = (_Float16)R2.y; h.z = (_Float16)R2.z; h.w = (_Float16)R2.w;
    *(half4_t*)(buf + wof2) = h;
  };

  const int l15 = lane & 15;
  const int g = lane >> 4;         // k-granule 0..3 (8 halves each)
  auto compute = [&](int par) {
    const _Float16* buf = &ldsb[par][0];
    half8_t fB[3];
#pragma unroll
    for (int j = 0; j < 3; ++j) {
      int rB = (wj * 3 + j) * 16 + l15;
      fB[j] = *(const half8_t*)(buf + rB * 32 + ((g ^ ((rB >> 1) & 3)) << 3));
    }
#pragma unroll
    for (int a = 0; a < 6; ++a) {
      int rA = (wi * 6 + a) * 16 + l15;
      half8_t fa = *(const half8_t*)(buf + rA * 32 + ((g ^ ((rA >> 1) & 3)) << 3));
#pragma unroll
      for (int j = 0; j < 3; ++j)
        acc[a][j] = __builtin_amdgcn_mfma_f32_16x16x32_f16(fa, fB[j], acc[a][j], 0, 0, 0);
    }
  };

  loadR(0);
  for (int cc = 0; cc < 16; ++cc) {
    writeL(cc & 1);                    // dep-waits on R loads (issued 1 chunk ago)
    asm volatile("s_waitcnt lgkmcnt(0)" ::: "memory");
    __builtin_amdgcn_sched_barrier(0);
    __builtin_amdgcn_s_barrier();      // raw barrier: vmcnt NOT drained
    if (cc + 1 < 16) loadR(cc + 1);    // in flight across barrier + compute
    compute(cc & 1);
  }

  // ---- flush Gram ----
  if (mode == 2) {
    float* pb = part + (size_t)(b * 128 + bx) * 37056;
#pragma unroll
    for (int a = 0; a < 6; ++a)
#pragma unroll
      for (int j = 0; j < 3; ++j) {
        int tt = (wi * 6 + a) * 12 + (wj * 3 + j);
        *(f32x4_t*)(pb + tt * 256 + lane * 4) = acc[a][j];
      }
  } else {
    float* Gb = G + b * 36864;
#pragma unroll
    for (int a = 0; a < 6; ++a)
#pragma unroll
      for (int j = 0; j < 3; ++j) {
#pragma unroll
        for (int r = 0; r < 4; ++r) {
          int gr = (wi * 6 + a) * 16 + ((lane >> 4) << 2) + r;
          int gc = (wj * 3 + j) * 16 + (lane & 15);
          atomicAdd(Gb + gr * 192 + gc, acc[a][j][r]);
        }
      }
  }

  // ---- row sums: scratch in buf0 (last compute read buf1) ----
  slds[(0 * 64 + rr) * 8 + c8] = sr0;
  slds[(1 * 64 + rr) * 8 + c8] = sr1;
  slds[(2 * 64 + rr) * 8 + c8] = sr2;
  __syncthreads();
  if (t < 192) {
    float v = 0.f;
#pragma unroll
    for (int q = 0; q < 8; ++q) v += slds[t * 8 + q];
    if (mode == 2)
      part[(size_t)(b * 128 + bx) * 37056 + 36864 + t] = v;
    else
      atomicAdd(S + b * 192 + t, v);
  }
}

// ---------------- K1.5: deterministic reduce of P partials/batch ----------------
__global__ void k1r_reduce(const float* __restrict__ part, float* __restrict__ G,
                           float* __restrict__ S, int P) {
  int idx = blockIdx.x * 256 + threadIdx.x;
  if (idx >= 4 * 37056) return;
  int b = idx / 37056;
  int flat = idx % 37056;
  const float* base = part + (size_t)b * P * 37056 + flat;
  float v0 = 0.f, v1 = 0.f, v2 = 0.f, v3 = 0.f;
  for (int q = 0; q < P; q += 4) {
    v0 += base[(size_t)(q + 0) * 37056];
    v1 += base[(size_t)(q + 1) * 37056];
    v2 += base[(size_t)(q + 2) * 37056];
    v3 += base[(size_t)(q + 3) * 37056];
  }
  float v = (v0 + v1) + (v2 + v3);
  if (flat < 36864) {
    int tt = flat >> 8;
    int I = tt / 12, J = tt % 12;
    int r = flat & 255;
    int lane = r >> 2, rg = r & 3;
    int row = I * 16 + ((lane >> 4) << 2) + rg;
    int col = J * 16 + (lane & 15);
    G[b * 36864 + row * 192 + col] = v;
  } else {
    S[b * 192 + (flat - 36864)] = v;
  }
}

// ---------------- K2: energy -> softmax -> M(fp16 swizzled), c0 ----------------
__global__ __launch_bounds__(256) void k2_small(
    const float* __restrict__ G, const float* __restrict__ S,
    const float* __restrict__ Wq, const float* __restrict__ bq,
    const float* __restrict__ Wk, const float* __restrict__ bk,
    const float* __restrict__ Wv, const float* __restrict__ bv,
    _Float16* __restrict__ Mh, float* __restrict__ c0w) {
  const int b = blockIdx.y;
  const int cbase = blockIdx.x * 8;
  const int t = threadIdx.x;
  __shared__ float T1[192 * 9];
  __shared__ float el[64 * 8];
  __shared__ float sq[8];
  __shared__ float sk[64];
  const float* Gb = G + b * 36864;
  const float* Sb = S + b * 192;

  if (t < 8) {
    float a = 0.f;
    const float* wq = Wq + (cbase + t) * 192;
    for (int i = 0; i < 192; ++i) a = fmaf(wq[i], Sb[i], a);
    sq[t] = a;
  } else if (t < 72) {
    int d = t - 8;
    float a = 0.f;
    const float* wk = Wk + d * 192;
    for (int j = 0; j < 192; ++j) a = fmaf(wk[j], Sb[j], a);
    sk[d] = a;
  }
  for (int e = t; e < 1536; e += 256) {
    int j = e % 192, cp = e / 192;
    const float* wq = Wq + (cbase + cp) * 192;
    float a = 0.f;
    for (int i = 0; i < 192; ++i) a = fmaf(wq[i], Gb[i * 192 + j], a);
    T1[j * 9 + cp] = a;
  }
  __syncthreads();
  for (int e = t; e < 512; e += 256) {
    int cp = e & 7, d = e >> 3;
    const float* wk = Wk + d * 192;
    float a = 0.f;
    for (int j = 0; j < 192; ++j) a = fmaf(T1[j * 9 + cp], wk[j], a);
    float bqc = bq[cbase + cp], bkd = bk[d];
    a += bqc * sk[d] + bkd * sq[cp] + 65536.0f * bqc * bkd;
    el[d * 8 + cp] = a * 0.125f;
  }
  __syncthreads();
  if (t < 8) {
    float mx = -3.0e38f;
    for (int d = 0; d < 64; ++d) mx = fmaxf(mx, el[d * 8 + t]);
    float sum = 0.f;
    for (int d = 0; d < 64; ++d) {
      float pv = expf(el[d * 8 + t] - mx);
      el[d * 8 + t] = pv;
      sum += pv;
    }
    float inv = 1.0f / sum;
    for (int d = 0; d < 64; ++d) el[d * 8 + t] *= inv;
  }
  __syncthreads();
  // M rows in fp16, swizzled exactly as K3's lds_m image: idx = c*192 + (i ^ ((c&7)<<3))
  for (int e = t; e < 1536; e += 256) {
    int i = e % 192, cp = e / 192;
    int c = cbase + cp;
    float a = 0.f;
    for (int d = 0; d < 64; ++d) a = fmaf(el[d * 8 + cp], Wv[d * 192 + i], a);
    Mh[(size_t)b * 12288 + c * 192 + (i ^ ((c & 7) << 3))] = (_Float16)a;
  }
  if (t < 8) {
    float a = 0.f;
    for (int d = 0; d < 64; ++d) a = fmaf(el[d * 8 + t], bv[d], a);
    c0w[b * 64 + cbase + t] = a;
  }
}

// ---------------- K3: out = M X + c0 (fp16 MFMA) ----------------
// grid (256, 4), block 256 (4 waves). Block: C[64 x 256n]; wave w: n-span w*64.
// X chunk [32 i][256 n] staged transposed into lds_x[n][32] fp16, swizzle i^=(n&3)<<3.
// M staged once (linear copy of pre-swizzled fp16 image). acc[4][4] = 64 VGPR.
__global__ __launch_bounds__(256, 3) void k3_out(
    const float* __restrict__ rgb, const float* __restrict__ hsv, const float* __restrict__ lab,
    const _Float16* __restrict__ Mh, const float* __restrict__ c0w, float* __restrict__ out) {
  __shared__ alignas(16) _Float16 lds_m[12288];
  __shared__ alignas(16) _Float16 lds_x[8192];
  __shared__ float c0l[64];
  const int t = threadIdx.x;
  const int lane = t & 63;
  const int w = t >> 6;
  const int b = blockIdx.y;
  const int nblk = blockIdx.x * 256;

  {  // stage M (24576 B) as 16B copies + c0
    const float4* msrc = (const float4*)(Mh + (size_t)b * 12288);
    float4* mdst = (float4*)lds_m;
#pragma unroll
    for (int k = 0; k < 6; ++k) mdst[t + 256 * k] = msrc[t + 256 * k];
    if (t < 64) c0l[t] = c0w[b * 64 + t];
  }

  const int xi = t & 31;   // i within chunk
  const int ng = t >> 5;   // 0..7: n-group of 32
  const float* srcs[3] = {rgb, hsv, lab};

  f32x4_t acc[4][4];
  const f32x4_t zero4 = {0.0f, 0.0f, 0.0f, 0.0f};
#pragma unroll
  for (int i = 0; i < 4; ++i)
#pragma unroll
    for (int j = 0; j < 4; ++j) acc[i][j] = zero4;

  float4 xr[8];
  auto xload = [&](int kc) {
    int ig = kc * 32 + xi;
    const float* p = srcs[ig >> 6] + (size_t)(b * 64 + (ig & 63)) * NPIX + nblk + ng * 32;
#pragma unroll
    for (int f = 0; f < 8; ++f) xr[f] = *(const float4*)(p + f * 4);
  };
  auto xwrite = [&]() {
#pragma unroll
    for (int f = 0; f < 8; ++f) {
      int n = ng * 32 + f * 4;
      lds_x[(n + 0) * 32 + (xi ^ 0)]  = (_Float16)xr[f].x;
      lds_x[(n + 1) * 32 + (xi ^ 8)]  = (_Float16)xr[f].y;
      lds_x[(n + 2) * 32 + (xi ^ 16)] = (_Float16)xr[f].z;
      lds_x[(n + 3) * 32 + (xi ^ 24)] = (_Float16)xr[f].w;
    }
  };

  const int g = lane >> 4;     // 0..3
  const int l15 = lane & 15;

  xload(0);
  for (int kc = 0; kc < 6; ++kc) {
    xwrite();
    __syncthreads();
    if (kc + 1 < 6) xload(kc + 1);
    half8_t fx[4], fm[4];
#pragma unroll
    for (int nt = 0; nt < 4; ++nt) {
      int n = w * 64 + nt * 16 + l15;
      fx[nt] = *(const half8_t*)(lds_x + n * 32 + ((8 * g) ^ ((n & 3) << 3)));
    }
#pragma unroll
    for (int ct = 0; ct < 4; ++ct) {
      int c = ct * 16 + l15;
      fm[ct] = *(const half8_t*)(lds_m + c * 192 + ((kc * 32 + 8 * g) ^ ((c & 7) << 3)));
    }
#pragma unroll
    for (int nt = 0; nt < 4; ++nt)
#pragma unroll
      for (int ct = 0; ct < 4; ++ct)
        acc[nt][ct] = __builtin_amdgcn_mfma_f32_16x16x32_f16(fx[nt], fm[ct], acc[nt][ct], 0, 0, 0);
    __syncthreads();
  }

  // epilogue: C-row (n) = 4*g + r from first operand, C-col (c) = l15 from second
#pragma unroll
  for (int ct = 0; ct < 4; ++ct) {
    int c = ct * 16 + l15;
    float c0v = c0l[c];
#pragma unroll
    for (int nt = 0; nt < 4; ++nt) {
      int n = nblk + w * 64 + nt * 16 + 4 * g;
      float4 o;
      o.x = acc[nt][ct][0] + c0v;
      o.y = acc[nt][ct][1] + c0v;
      o.z = acc[nt][ct][2] + c0v;
      o.w = acc[nt][ct][3] + c0v;
      *(float4*)(out + (size_t)(b * 64 + c) * NPIX + n) = o;
    }
  }
}

extern "C" void kernel_launch(void* const* d_in, const int* in_sizes, int n_in,
                              void* d_out, int out_size, void* d_ws, size_t ws_size,
                              hipStream_t stream) {
  const float* rgb = (const float*)d_in[0];
  const float* hsv = (const float*)d_in[1];
  const float* lab = (const float*)d_in[2];
  const float* Wq = (const float*)d_in[3];
  const float* bq = (const float*)d_in[4];
  const float* Wk = (const float*)d_in[5];
  const float* bk = (const float*)d_in[6];
  const float* Wv = (const float*)d_in[7];
  const float* bv = (const float*)d_in[8];
  float* out = (float*)d_out;
  float* ws = (float*)d_ws;

  float* G = ws;                            // 147456 f32
  float* S = ws + 147456;                   // 768
  _Float16* Mh = (_Float16*)(ws + 148224);  // 49152 halves = 24576 f32 slots
  float* c0w = ws + 172800;                 // 256
  float* part = ws + 173056;                // 512*37056 f32 (128 slots x 4 batches)
  const size_t need2 = (size_t)(173056 + 512 * 37056) * 4;  // 75.9 MB
  const int mode = ws_size >= need2 ? 2 : 0;

  if (mode == 0)
    k0_zero<<<dim3(579), dim3(256), 0, stream>>>(ws, 148224);  // zero G + S

  k1_gram<<<dim3(128, 4), dim3(512), 0, stream>>>(rgb, hsv, lab, G, S, part, mode);
  if (mode)
    k1r_reduce<<<dim3(579), dim3(256), 0, stream>>>(part, G, S, 128);
  k2_small<<<dim3(8, 4), dim3(256), 0, stream>>>(G, S, Wq, bq, Wk, bk, Wv, bv, Mh, c0w);
  k3_out<<<dim3(256, 4), dim3(256), 0, stream>>>(rgb, hsv, lab, Mh, c0w, out);
}

// Round 10
// 152.257 us; speedup vs baseline: 1.1507x; 1.0965x over previous
//
#include <hip/hip_runtime.h>
#include <cstddef>

// CAM module, algebraically restructured:
//   X = concat(rgb,hsv,lab) : [B=4, 192, N=65536] (f32)
//   G[b] = X X^T (192x192), s[b] = row sums        (K1, fp16 MFMA, DMA + counted vmcnt)
//   energy = (Wq G Wk^T + bq sk^T + sq bk^T + N bq bk^T)/8 ; att = softmax_d
//   M = att Wv (emitted as swizzled fp16) ; c0 = att bv   (K2, f32)
//   out = M X + c0                                  (K3, fp16 MFMA, memory-bound)
//
// R3..R9 post-mortem: six K1 variants all ~85-95 us with NO pipe busy. Shared
// defect: per-chunk FULL vmcnt drain (R7/R8 waited vmcnt(0) -> next chunk's DMA
// must complete inside the chunk; memory idles during compute). This round is
// the guide's T3/T4 pattern done right: 4 LDS buffers, depth-3 DMA prefetch,
// per-chunk s_waitcnt vmcnt(4) (stage cc drained, cc+1/cc+2 stay IN FLIGHT
// across the barrier), epilogue peels vmcnt(2)/vmcnt(0) (in-order retirement).

#define NPIX 65536

typedef _Float16 half8_t __attribute__((ext_vector_type(8)));
typedef float f32x4_t __attribute__((ext_vector_type(4)));

// ---------------- K0: zero a float range ----------------
__global__ void k0_zero(float* __restrict__ p, int n) {
  int i = blockIdx.x * 256 + threadIdx.x;
  if (i < n) p[i] = 0.0f;
}

// ---------------- K1: Gram + row sums ----------------
// grid (64, 4) = 256 blocks, block 768 (12 waves as 3x4).
// 1024 cols/block, 32 chunks of 32 f32 cols. LDS: 4 x [192][32] f32 (24 KB each).
// Staging: global_load_lds dwordx4, swizzle baked into per-lane SOURCE address
// (LDS dest linear): granule g holds X[row][4*(g^(row&7))].
// Pipeline: prologue stages chunks 0..2; loop cc: vmcnt(4) [chunk cc landed,
// cc+1/cc+2 in flight] -> s_barrier -> stage(cc+3) -> compute(cc).
// Wave (wi,wj) in 3x4: A-tiles wi*4+a (a<4), B-tiles wj*3+j (j<3); acc[4][3].
// mode: 1 = direct partials (64 slots/batch), 0 = atomicAdd into zeroed G/S.
__global__ __launch_bounds__(768) void k1_gram(
    const float* __restrict__ rgb, const float* __restrict__ hsv, const float* __restrict__ lab,
    float* __restrict__ G, float* __restrict__ S, float* __restrict__ part, int mode) {
  __shared__ alignas(16) float ldsb[4][6144];  // 4 x 24 KB

  const int t = threadIdx.x;
  const int lane = t & 63;
  const int w = t >> 6;            // 0..11
  const int wi = w >> 2;           // 0..2: A row-group (4 tiles = 64 rows)
  const int wj = w & 3;            // 0..3: B col-group (3 tiles = 48 rows)
  const int b = blockIdx.y;
  const int bx = blockIdx.x;       // 0..63
  const int n0 = bx * 1024;

  // staging source addresses (2 DMA rounds per chunk):
  // round r: wave stages rows w*16+r*8 .. +7 (8 rows x 128 B = 1 KB).
  // lane l -> row = w*16 + r*8 + (l>>3), granule g = l&7; source granule
  // sg = g ^ (row&7)  (XOR swizzle baked into source address; LDS dest linear).
  const float* gsrc[2];
#pragma unroll
  for (int r = 0; r < 2; ++r) {
    int row = w * 16 + r * 8 + (lane >> 3);
    int rs = row >> 6;  // uniform per (w,r): 8-row groups never straddle 64
    const float* sp = (rs == 0) ? rgb : (rs == 1) ? hsv : lab;
    int sg = (lane & 7) ^ (row & 7);
    gsrc[r] = sp + (size_t)(b * 64 + (row & 63)) * NPIX + n0 + 4 * sg;
  }

  f32x4_t acc[4][3];
  const f32x4_t zero4 = {0.0f, 0.0f, 0.0f, 0.0f};
#pragma unroll
  for (int a = 0; a < 4; ++a)
#pragma unroll
    for (int j = 0; j < 3; ++j) acc[a][j] = zero4;

  float srow = 0.0f;                 // row-sum partial: row t>>2, quarter t&3
  const int sr_r = t >> 2;
  const int sr_q = t & 3;

  const int l15 = lane & 15;
  const int gk = 2 * (lane >> 4);    // fragment granule base (k = 8*(lane>>4) f32)

  auto stage = [&](int cc) {
    const int par = cc & 3;
#pragma unroll
    for (int r = 0; r < 2; ++r) {
      __builtin_amdgcn_global_load_lds(
          (const __attribute__((address_space(1))) void*)(gsrc[r] + cc * 32),
          (__attribute__((address_space(3))) void*)(&ldsb[par][(w * 16 + r * 8) * 32]),
          16, 0, 0);
    }
  };

  auto compute = [&](int cc) {
    const int par = cc & 3;
    half8_t fB16[3];
#pragma unroll
    for (int j = 0; j < 3; ++j) {
      int rB = (wj * 3 + j) * 16 + l15;
      f32x4_t lo = *(const f32x4_t*)(&ldsb[par][rB * 32 + ((gk ^ (rB & 7)) << 2)]);
      f32x4_t hi = *(const f32x4_t*)(&ldsb[par][rB * 32 + (((gk + 1) ^ (rB & 7)) << 2)]);
      half8_t f;
      f[0] = (_Float16)lo[0]; f[1] = (_Float16)lo[1];
      f[2] = (_Float16)lo[2]; f[3] = (_Float16)lo[3];
      f[4] = (_Float16)hi[0]; f[5] = (_Float16)hi[1];
      f[6] = (_Float16)hi[2]; f[7] = (_Float16)hi[3];
      fB16[j] = f;
    }
#pragma unroll
    for (int a = 0; a < 4; ++a) {
      int rA = (wi * 4 + a) * 16 + l15;
      f32x4_t lo = *(const f32x4_t*)(&ldsb[par][rA * 32 + ((gk ^ (rA & 7)) << 2)]);
      f32x4_t hi = *(const f32x4_t*)(&ldsb[par][rA * 32 + (((gk + 1) ^ (rA & 7)) << 2)]);
      half8_t fa;
      fa[0] = (_Float16)lo[0]; fa[1] = (_Float16)lo[1];
      fa[2] = (_Float16)lo[2]; fa[3] = (_Float16)lo[3];
      fa[4] = (_Float16)hi[0]; fa[5] = (_Float16)hi[1];
      fa[6] = (_Float16)hi[2]; fa[7] = (_Float16)hi[3];
#pragma unroll
      for (int j = 0; j < 3; ++j)
        acc[a][j] = __builtin_amdgcn_mfma_f32_16x16x32_f16(fa, fB16[j], acc[a][j], 0, 0, 0);
    }
    // row sums: this thread's 8 f32 of (row sr_r, logical granules 2q, 2q+1)
    {
      f32x4_t s0 = *(const f32x4_t*)(&ldsb[par][sr_r * 32 + (((2 * sr_q) ^ (sr_r & 7)) << 2)]);
      f32x4_t s1 = *(const f32x4_t*)(&ldsb[par][sr_r * 32 + (((2 * sr_q + 1) ^ (sr_r & 7)) << 2)]);
      srow += (s0[0] + s0[1]) + (s0[2] + s0[3]) + (s1[0] + s1[1]) + (s1[2] + s1[3]);
    }
  };

  // ---- prologue: 3 chunks in flight ----
  stage(0); stage(1); stage(2);
  // ---- main loop: counted vmcnt, loads live across barriers ----
  for (int cc = 0; cc < 30; ++cc) {
    asm volatile("s_waitcnt vmcnt(4)" ::: "memory");  // chunk cc landed
    __builtin_amdgcn_sched_barrier(0);
    __builtin_amdgcn_s_barrier();
    if (cc + 3 < 32) stage(cc + 3);   // into buf[(cc+3)&3], freed by compute(cc-1)
    compute(cc);
  }
  // ---- epilogue (in-order vmcnt retirement: 30 needs vmcnt(2), 31 needs 0) ----
  asm volatile("s_waitcnt vmcnt(2)" ::: "memory");
  __builtin_amdgcn_sched_barrier(0);
  __builtin_amdgcn_s_barrier();
  compute(30);
  asm volatile("s_waitcnt vmcnt(0)" ::: "memory");
  __builtin_amdgcn_sched_barrier(0);
  __builtin_amdgcn_s_barrier();
  compute(31);

  // ---- flush Gram ----
  if (mode) {
    float* pb = part + (size_t)(b * 64 + bx) * 37056;
#pragma unroll
    for (int a = 0; a < 4; ++a)
#pragma unroll
      for (int j = 0; j < 3; ++j) {
        int tt = (wi * 4 + a) * 12 + (wj * 3 + j);
        *(f32x4_t*)(pb + tt * 256 + lane * 4) = acc[a][j];
      }
  } else {
    float* Gb = G + b * 36864;
#pragma unroll
    for (int a = 0; a < 4; ++a)
#pragma unroll
      for (int j = 0; j < 3; ++j) {
#pragma unroll
        for (int r = 0; r < 4; ++r) {
          int gr = (wi * 4 + a) * 16 + ((lane >> 4) << 2) + r;
          int gc = (wj * 3 + j) * 16 + (lane & 15);
          atomicAdd(Gb + gr * 192 + gc, acc[a][j][r]);
        }
      }
  }

  // ---- row sums: reduce 4 quarters/row via LDS buf0 (free after last compute) ----
  float* slds = &ldsb[0][0];
  __syncthreads();
  slds[t] = srow;
  __syncthreads();
  if (t < 192) {
    float v = (slds[4 * t] + slds[4 * t + 1]) + (slds[4 * t + 2] + slds[4 * t + 3]);
    if (mode)
      part[(size_t)(b * 64 + bx) * 37056 + 36864 + t] = v;
    else
      atomicAdd(S + b * 192 + t, v);
  }
}

// ---------------- K1.5: deterministic reduce of P partials/batch ----------------
__global__ void k1r_reduce(const float* __restrict__ part, float* __restrict__ G,
                           float* __restrict__ S, int P) {
  int idx = blockIdx.x * 256 + threadIdx.x;
  if (idx >= 4 * 37056) return;
  int b = idx / 37056;
  int flat = idx % 37056;
  const float* base = part + (size_t)b * P * 37056 + flat;
  float v0 = 0.f, v1 = 0.f, v2 = 0.f, v3 = 0.f;
  for (int q = 0; q < P; q += 4) {
    v0 += base[(size_t)(q + 0) * 37056];
    v1 += base[(size_t)(q + 1) * 37056];
    v2 += base[(size_t)(q + 2) * 37056];
    v3 += base[(size_t)(q + 3) * 37056];
  }
  float v = (v0 + v1) + (v2 + v3);
  if (flat < 36864) {
    int tt = flat >> 8;
    int I = tt / 12, J = tt % 12;
    int r = flat & 255;
    int lane = r >> 2, rg = r & 3;
    int row = I * 16 + ((lane >> 4) << 2) + rg;
    int col = J * 16 + (lane & 15);
    G[b * 36864 + row * 192 + col] = v;
  } else {
    S[b * 192 + (flat - 36864)] = v;
  }
}

// ---------------- K2: energy -> softmax -> M(fp16 swizzled), c0 ----------------
__global__ __launch_bounds__(256) void k2_small(
    const float* __restrict__ G, const float* __restrict__ S,
    const float* __restrict__ Wq, const float* __restrict__ bq,
    const float* __restrict__ Wk, const float* __restrict__ bk,
    const float* __restrict__ Wv, const float* __restrict__ bv,
    _Float16* __restrict__ Mh, float* __restrict__ c0w) {
  const int b = blockIdx.y;
  const int cbase = blockIdx.x * 8;
  const int t = threadIdx.x;
  __shared__ float T1[192 * 9];
  __shared__ float el[64 * 8];
  __shared__ float sq[8];
  __shared__ float sk[64];
  const float* Gb = G + b * 36864;
  const float* Sb = S + b * 192;

  if (t < 8) {
    float a = 0.f;
    const float* wq = Wq + (cbase + t) * 192;
    for (int i = 0; i < 192; ++i) a = fmaf(wq[i], Sb[i], a);
    sq[t] = a;
  } else if (t < 72) {
    int d = t - 8;
    float a = 0.f;
    const float* wk = Wk + d * 192;
    for (int j = 0; j < 192; ++j) a = fmaf(wk[j], Sb[j], a);
    sk[d] = a;
  }
  for (int e = t; e < 1536; e += 256) {
    int j = e % 192, cp = e / 192;
    const float* wq = Wq + (cbase + cp) * 192;
    float a = 0.f;
    for (int i = 0; i < 192; ++i) a = fmaf(wq[i], Gb[i * 192 + j], a);
    T1[j * 9 + cp] = a;
  }
  __syncthreads();
  for (int e = t; e < 512; e += 256) {
    int cp = e & 7, d = e >> 3;
    const float* wk = Wk + d * 192;
    float a = 0.f;
    for (int j = 0; j < 192; ++j) a = fmaf(T1[j * 9 + cp], wk[j], a);
    float bqc = bq[cbase + cp], bkd = bk[d];
    a += bqc * sk[d] + bkd * sq[cp] + 65536.0f * bqc * bkd;
    el[d * 8 + cp] = a * 0.125f;
  }
  __syncthreads();
  if (t < 8) {
    float mx = -3.0e38f;
    for (int d = 0; d < 64; ++d) mx = fmaxf(mx, el[d * 8 + t]);
    float sum = 0.f;
    for (int d = 0; d < 64; ++d) {
      float pv = expf(el[d * 8 + t] - mx);
      el[d * 8 + t] = pv;
      sum += pv;
    }
    float inv = 1.0f / sum;
    for (int d = 0; d < 64; ++d) el[d * 8 + t] *= inv;
  }
  __syncthreads();
  // M rows in fp16, swizzled exactly as K3's lds_m image: idx = c*192 + (i ^ ((c&7)<<3))
  for (int e = t; e < 1536; e += 256) {
    int i = e % 192, cp = e / 192;
    int c = cbase + cp;
    float a = 0.f;
    for (int d = 0; d < 64; ++d) a = fmaf(el[d * 8 + cp], Wv[d * 192 + i], a);
    Mh[(size_t)b * 12288 + c * 192 + (i ^ ((c & 7) << 3))] = (_Float16)a;
  }
  if (t < 8) {
    float a = 0.f;
    for (int d = 0; d < 64; ++d) a = fmaf(el[d * 8 + t], bv[d], a);
    c0w[b * 64 + cbase + t] = a;
  }
}

// ---------------- K3: out = M X + c0 (fp16 MFMA) ----------------
// grid (256, 4), block 256 (4 waves). Block: C[64 x 256n]; wave w: n-span w*64.
// X chunk [32 i][256 n] staged transposed into lds_x[n][32] fp16, swizzle i^=(n&3)<<3.
// M staged once (linear copy of pre-swizzled fp16 image). acc[4][4] = 64 VGPR.
__global__ __launch_bounds__(256, 3) void k3_out(
    const float* __restrict__ rgb, const float* __restrict__ hsv, const float* __restrict__ lab,
    const _Float16* __restrict__ Mh, const float* __restrict__ c0w, float* __restrict__ out) {
  __shared__ alignas(16) _Float16 lds_m[12288];
  __shared__ alignas(16) _Float16 lds_x[8192];
  __shared__ float c0l[64];
  const int t = threadIdx.x;
  const int lane = t & 63;
  const int w = t >> 6;
  const int b = blockIdx.y;
  const int nblk = blockIdx.x * 256;

  {  // stage M (24576 B) as 16B copies + c0
    const float4* msrc = (const float4*)(Mh + (size_t)b * 12288);
    float4* mdst = (float4*)lds_m;
#pragma unroll
    for (int k = 0; k < 6; ++k) mdst[t + 256 * k] = msrc[t + 256 * k];
    if (t < 64) c0l[t] = c0w[b * 64 + t];
  }

  const int xi = t & 31;   // i within chunk
  const int ng = t >> 5;   // 0..7: n-group of 32
  const float* srcs[3] = {rgb, hsv, lab};

  f32x4_t acc[4][4];
  const f32x4_t zero4 = {0.0f, 0.0f, 0.0f, 0.0f};
#pragma unroll
  for (int i = 0; i < 4; ++i)
#pragma unroll
    for (int j = 0; j < 4; ++j) acc[i][j] = zero4;

  float4 xr[8];
  auto xload = [&](int kc) {
    int ig = kc * 32 + xi;
    const float* p = srcs[ig >> 6] + (size_t)(b * 64 + (ig & 63)) * NPIX + nblk + ng * 32;
#pragma unroll
    for (int f = 0; f < 8; ++f) xr[f] = *(const float4*)(p + f * 4);
  };
  auto xwrite = [&]() {
#pragma unroll
    for (int f = 0; f < 8; ++f) {
      int n = ng * 32 + f * 4;
      lds_x[(n + 0) * 32 + (xi ^ 0)]  = (_Float16)xr[f].x;
      lds_x[(n + 1) * 32 + (xi ^ 8)]  = (_Float16)xr[f].y;
      lds_x[(n + 2) * 32 + (xi ^ 16)] = (_Float16)xr[f].z;
      lds_x[(n + 3) * 32 + (xi ^ 24)] = (_Float16)xr[f].w;
    }
  };

  const int g = lane >> 4;     // 0..3
  const int l15 = lane & 15;

  xload(0);
  for (int kc = 0; kc < 6; ++kc) {
    xwrite();
    __syncthreads();
    if (kc + 1 < 6) xload(kc + 1);
    half8_t fx[4], fm[4];
#pragma unroll
    for (int nt = 0; nt < 4; ++nt) {
      int n = w * 64 + nt * 16 + l15;
      fx[nt] = *(const half8_t*)(lds_x + n * 32 + ((8 * g) ^ ((n & 3) << 3)));
    }
#pragma unroll
    for (int ct = 0; ct < 4; ++ct) {
      int c = ct * 16 + l15;
      fm[ct] = *(const half8_t*)(lds_m + c * 192 + ((kc * 32 + 8 * g) ^ ((c & 7) << 3)));
    }
#pragma unroll
    for (int nt = 0; nt < 4; ++nt)
#pragma unroll
      for (int ct = 0; ct < 4; ++ct)
        acc[nt][ct] = __builtin_amdgcn_mfma_f32_16x16x32_f16(fx[nt], fm[ct], acc[nt][ct], 0, 0, 0);
    __syncthreads();
  }

  // epilogue: C-row (n) = 4*g + r from first operand, C-col (c) = l15 from second
#pragma unroll
  for (int ct = 0; ct < 4; ++ct) {
    int c = ct * 16 + l15;
    float c0v = c0l[c];
#pragma unroll
    for (int nt = 0; nt < 4; ++nt) {
      int n = nblk + w * 64 + nt * 16 + 4 * g;
      float4 o;
      o.x = acc[nt][ct][0] + c0v;
      o.y = acc[nt][ct][1] + c0v;
      o.z = acc[nt][ct][2] + c0v;
      o.w = acc[nt][ct][3] + c0v;
      *(float4*)(out + (size_t)(b * 64 + c) * NPIX + n) = o;
    }
  }
}

extern "C" void kernel_launch(void* const* d_in, const int* in_sizes, int n_in,
                              void* d_out, int out_size, void* d_ws, size_t ws_size,
                              hipStream_t stream) {
  const float* rgb = (const float*)d_in[0];
  const float* hsv = (const float*)d_in[1];
  const float* lab = (const float*)d_in[2];
  const float* Wq = (const float*)d_in[3];
  const float* bq = (const float*)d_in[4];
  const float* Wk = (const float*)d_in[5];
  const float* bk = (const float*)d_in[6];
  const float* Wv = (const float*)d_in[7];
  const float* bv = (const float*)d_in[8];
  float* out = (float*)d_out;
  float* ws = (float*)d_ws;

  float* G = ws;                            // 147456 f32
  float* S = ws + 147456;                   // 768
  _Float16* Mh = (_Float16*)(ws + 148224);  // 49152 halves = 24576 f32 slots
  float* c0w = ws + 172800;                 // 256
  float* part = ws + 173056;                // 256*37056 f32 (64 slots x 4 batches)
  const size_t need1 = (size_t)(173056 + 256 * 37056) * 4;  // 38.6 MB
  const int mode = ws_size >= need1 ? 1 : 0;

  if (!mode)
    k0_zero<<<dim3(579), dim3(256), 0, stream>>>(ws, 148224);  // zero G + S

  k1_gram<<<dim3(64, 4), dim3(768), 0, stream>>>(rgb, hsv, lab, G, S, part, mode);
  if (mode)
    k1r_reduce<<<dim3(579), dim3(256), 0, stream>>>(part, G, S, 64);
  k2_small<<<dim3(8, 4), dim3(256), 0, stream>>>(G, S, Wq, bq, Wk, bk, Wv, bv, Mh, c0w);
  k3_out<<<dim3(256, 4), dim3(256), 0, stream>>>(rgb, hsv, lab, Mh, c0w, out);
}

// Round 11
// 147.674 us; speedup vs baseline: 1.1864x; 1.0310x over previous
//
#include <hip/hip_runtime.h>
#include <cstddef>

// CAM module, algebraically restructured:
//   X = concat(rgb,hsv,lab) : [B=4, 192, N=65536] (f32)
//   G[b] = X X^T (192x192 symmetric, upper block-triangle computed), s[b] = row sums
//   energy = (Wq G Wk^T + bq sk^T + sq bk^T + N bq bk^T)/8 ; att = softmax_d
//   M = att Wv (emitted as swizzled fp16) ; c0 = att bv   (K2, f32)
//   out = M X + c0                                  (K3, fp16 MFMA, ~5 TB/s measured)
//
// R3-R10 lesson: seven K1 variants (reg-staged / DMA / fp16-LDS / counted-vmcnt
// pipeline) ALL landed at 85-95 us. Common trait: one 12-wave block per CU
// (unified VGPR+AGPR ~116 -> 3 waves/SIMD -> no 2nd block fits) -> every
// barrier/drain stalls the whole CU. K3 (268 MB in <50 us) uses 4 independent
// 4-wave blocks/CU with plain __syncthreads. This round K1 copies K3's shape:
// 8-wave blocks, triangle-only tiles (acc 40 AGPR), unified ~95 <= 128 ->
// 2 blocks/CU, single-buffer LDS + 2 barriers/chunk, 1-deep reg prefetch.

#define NPIX 65536

typedef _Float16 half4_t __attribute__((ext_vector_type(4)));
typedef _Float16 half8_t __attribute__((ext_vector_type(8)));
typedef float f32x4_t __attribute__((ext_vector_type(4)));

// upper block-triangle (I<=J) of the 12x12 tile grid, row-major: 78 tiles.
constexpr int TRI_I[78] = {
  0,0,0,0,0,0,0,0,0,0,0,0,
  1,1,1,1,1,1,1,1,1,1,1,
  2,2,2,2,2,2,2,2,2,2,
  3,3,3,3,3,3,3,3,3,
  4,4,4,4,4,4,4,4,
  5,5,5,5,5,5,5,
  6,6,6,6,6,6,
  7,7,7,7,7,
  8,8,8,8,
  9,9,9,
  10,10,
  11};
constexpr int TRI_J[78] = {
  0,1,2,3,4,5,6,7,8,9,10,11,
  1,2,3,4,5,6,7,8,9,10,11,
  2,3,4,5,6,7,8,9,10,11,
  3,4,5,6,7,8,9,10,11,
  4,5,6,7,8,9,10,11,
  5,6,7,8,9,10,11,
  6,7,8,9,10,11,
  7,8,9,10,11,
  8,9,10,11,
  9,10,11,
  10,11,
  11};

#define PSZ 20160  // per-slot partial: 78*256 triangle + 192 rowsums

// ---------------- K0: zero a float range ----------------
__global__ void k0_zero(float* __restrict__ p, int n) {
  int i = blockIdx.x * 256 + threadIdx.x;
  if (i < n) p[i] = 0.0f;
}

// ---- per-wave MFMA over a static contiguous triangle-tile run ----
template <int BASE, int CNT>
__device__ __forceinline__ void mfma_run(const _Float16* __restrict__ buf,
                                         f32x4_t* __restrict__ acc, int l15, int g) {
  half8_t fA;
#pragma unroll
  for (int tt = 0; tt < CNT; ++tt) {
    const int t = BASE + tt;           // compile-time after unroll
    if (tt == 0 || TRI_I[t] != TRI_I[t - 1]) {
      int rA = TRI_I[t] * 16 + l15;
      fA = *(const half8_t*)(buf + rA * 32 + ((g ^ ((rA >> 1) & 3)) << 3));
    }
    int rB = TRI_J[t] * 16 + l15;
    half8_t fB = *(const half8_t*)(buf + rB * 32 + ((g ^ ((rB >> 1) & 3)) << 3));
    acc[tt] = __builtin_amdgcn_mfma_f32_16x16x32_f16(fA, fB, acc[tt], 0, 0, 0);
  }
}

template <int BASE, int CNT>
__device__ __forceinline__ void flush_part(const f32x4_t* __restrict__ acc,
                                           float* __restrict__ pb, int lane) {
#pragma unroll
  for (int tt = 0; tt < CNT; ++tt)
    *(f32x4_t*)(pb + (BASE + tt) * 256 + lane * 4) = acc[tt];
}

template <int BASE, int CNT>
__device__ __forceinline__ void flush_atomic(const f32x4_t* __restrict__ acc,
                                             float* __restrict__ Gb, int lane) {
#pragma unroll
  for (int tt = 0; tt < CNT; ++tt) {
    const int t = BASE + tt;
#pragma unroll
    for (int r = 0; r < 4; ++r) {
      int gr = TRI_I[t] * 16 + ((lane >> 4) << 2) + r;
      int gc = TRI_J[t] * 16 + (lane & 15);
      atomicAdd(Gb + gr * 192 + gc, acc[tt][r]);
    }
  }
}

// ---------------- K1: Gram (triangle) + row sums ----------------
// grid (128, 4) = 512 blocks, block 512 (8 waves). 512 cols/block, 16 chunks
// of 32 cols. LDS: single [192][32] fp16 buffer (12 KB), R9's measured
// conflict-free layout: halves granule G at row*32 + ((G^((row>>1)&3))<<3).
// K3-pattern loop: writeLDS; sync; load(next); compute; sync.
// Wave w owns triangle tiles [w*10, w*10+10) (wave 7: 8 tiles). acc <= 40 AGPR.
// mode: 1 = direct partials (128 slots/batch), 0 = atomicAdd into zeroed G/S.
__global__ __launch_bounds__(512) void k1_gram(
    const float* __restrict__ rgb, const float* __restrict__ hsv, const float* __restrict__ lab,
    float* __restrict__ G, float* __restrict__ S, float* __restrict__ part, int mode) {
  __shared__ alignas(16) _Float16 lds[6144];  // 12 KB
  float* slds = (float*)lds;

  const int t = threadIdx.x;
  const int lane = t & 63;
  const int w = t >> 6;           // 0..7
  const int b = blockIdx.y;
  const int bx = blockIdx.x;      // 0..127
  const int n0 = bx * 512;

  // staging map: thread -> granule gq = t&7 (4 f32), base row r6 = t>>3 (0..63);
  // covers rows {r6, 64+r6, 128+r6} from rgb/hsv/lab respectively.
  const int gq = t & 7;
  const int r6 = t >> 3;
  const float* gp0 = rgb + (size_t)(b * 64 + r6) * NPIX + n0 + 4 * gq;
  const float* gp1 = hsv + (size_t)(b * 64 + r6) * NPIX + n0 + 4 * gq;
  const float* gp2 = lab + (size_t)(b * 64 + r6) * NPIX + n0 + 4 * gq;
  // write offset: swizzle depends on (row>>1)&3 = (r6>>1)&3 (row=rep*64+r6, rep*32%4==0)
  const int wsw = (((gq >> 1) ^ ((r6 >> 1) & 3)) << 3) + (gq & 1) * 4;
  const int wof0 = (0 * 64 + r6) * 32 + wsw;
  const int wof1 = (1 * 64 + r6) * 32 + wsw;
  const int wof2 = (2 * 64 + r6) * 32 + wsw;

  f32x4_t acc[10];
  const f32x4_t zero4 = {0.0f, 0.0f, 0.0f, 0.0f};
#pragma unroll
  for (int i = 0; i < 10; ++i) acc[i] = zero4;
  float sr0 = 0.f, sr1 = 0.f, sr2 = 0.f;

  float4 P0, P1, P2;
  auto loadR = [&](int cc) {
    P0 = *(const float4*)(gp0 + cc * 32);
    P1 = *(const float4*)(gp1 + cc * 32);
    P2 = *(const float4*)(gp2 + cc * 32);
  };
  auto writeL = [&]() {
    half4_t h;
    sr0 += (P0.x + P0.y) + (P0.z + P0.w);
    h.x = (_Float16)P0.x; h.y = (_Float16)P0.y; h.z = (_Float16)P0.z; h.w = (_Float16)P0.w;
    *(half4_t*)(lds + wof0) = h;
    sr1 += (P1.x + P1.y) + (P1.z + P1.w);
    h.x = (_Float16)P1.x; h.y = (_Float16)P1.y; h.z = (_Float16)P1.z; h.w = (_Float16)P1.w;
    *(half4_t*)(lds + wof1) = h;
    sr2 += (P2.x + P2.y) + (P2.z + P2.w);
    h.x = (_Float16)P2.x; h.y = (_Float16)P2.y; h.z = (_Float16)P2.z; h.w = (_Float16)P2.w;
    *(half4_t*)(lds + wof2) = h;
  };

  const int l15 = lane & 15;
  const int g = lane >> 4;

  loadR(0);
  for (int cc = 0; cc < 16; ++cc) {
    writeL();                        // waits on P (loads from prev iteration)
    __syncthreads();
    if (cc + 1 < 16) loadR(cc + 1);  // in flight under compute (K3 pattern)
    switch (w) {
      case 0: mfma_run<0, 10>(lds, acc, l15, g); break;
      case 1: mfma_run<10, 10>(lds, acc, l15, g); break;
      case 2: mfma_run<20, 10>(lds, acc, l15, g); break;
      case 3: mfma_run<30, 10>(lds, acc, l15, g); break;
      case 4: mfma_run<40, 10>(lds, acc, l15, g); break;
      case 5: mfma_run<50, 10>(lds, acc, l15, g); break;
      case 6: mfma_run<60, 10>(lds, acc, l15, g); break;
      case 7: mfma_run<70, 8>(lds, acc, l15, g); break;
    }
    __syncthreads();
  }

  // ---- flush Gram (this block's 78 triangle tiles across 8 waves) ----
  if (mode) {
    float* pb = part + (size_t)(b * 128 + bx) * PSZ;
    switch (w) {
      case 0: flush_part<0, 10>(acc, pb, lane); break;
      case 1: flush_part<10, 10>(acc, pb, lane); break;
      case 2: flush_part<20, 10>(acc, pb, lane); break;
      case 3: flush_part<30, 10>(acc, pb, lane); break;
      case 4: flush_part<40, 10>(acc, pb, lane); break;
      case 5: flush_part<50, 10>(acc, pb, lane); break;
      case 6: flush_part<60, 10>(acc, pb, lane); break;
      case 7: flush_part<70, 8>(acc, pb, lane); break;
    }
  } else {
    float* Gb = G + b * 36864;
    switch (w) {
      case 0: flush_atomic<0, 10>(acc, Gb, lane); break;
      case 1: flush_atomic<10, 10>(acc, Gb, lane); break;
      case 2: flush_atomic<20, 10>(acc, Gb, lane); break;
      case 3: flush_atomic<30, 10>(acc, Gb, lane); break;
      case 4: flush_atomic<40, 10>(acc, Gb, lane); break;
      case 5: flush_atomic<50, 10>(acc, Gb, lane); break;
      case 6: flush_atomic<60, 10>(acc, Gb, lane); break;
      case 7: flush_atomic<70, 8>(acc, Gb, lane); break;
    }
  }

  // ---- row sums: reuse LDS as f32 scratch (compute fully done after loop) ----
  slds[(0 * 64 + r6) * 8 + gq] = sr0;
  slds[(1 * 64 + r6) * 8 + gq] = sr1;
  slds[(2 * 64 + r6) * 8 + gq] = sr2;
  __syncthreads();
  if (t < 192) {
    float v = 0.f;
#pragma unroll
    for (int q = 0; q < 8; ++q) v += slds[t * 8 + q];
    if (mode)
      part[(size_t)(b * 128 + bx) * PSZ + 19968 + t] = v;
    else
      atomicAdd(S + b * 192 + t, v);
  }
}

// ---------------- K1.5a: deterministic reduce of 128 partials + mirror ----------------
__global__ void k1r_reduce(const float* __restrict__ part, float* __restrict__ G,
                           float* __restrict__ S) {
  int idx = blockIdx.x * 256 + threadIdx.x;
  if (idx >= 4 * PSZ) return;
  int b = idx / PSZ;
  int flat = idx % PSZ;
  const float* base = part + (size_t)b * 128 * PSZ + flat;
  float v0 = 0.f, v1 = 0.f, v2 = 0.f, v3 = 0.f;
#pragma unroll 4
  for (int q = 0; q < 128; q += 4) {
    v0 += base[(size_t)(q + 0) * PSZ];
    v1 += base[(size_t)(q + 1) * PSZ];
    v2 += base[(size_t)(q + 2) * PSZ];
    v3 += base[(size_t)(q + 3) * PSZ];
  }
  float v = (v0 + v1) + (v2 + v3);
  if (flat < 19968) {
    int tt = flat >> 8;
    int r = flat & 255;
    int lane = r >> 2, rg = r & 3;
    int row = TRI_I[tt] * 16 + ((lane >> 4) << 2) + rg;
    int col = TRI_J[tt] * 16 + (lane & 15);
    float* Gb = G + b * 36864;
    Gb[row * 192 + col] = v;
    Gb[col * 192 + row] = v;  // mirror (diagonal tiles: benign double-write)
  } else {
    S[b * 192 + (flat - 19968)] = v;
  }
}

// ---------------- K1.5b (atomic fallback): mirror lower block-triangle ----------------
__global__ void k1m_mirror(float* __restrict__ G) {
  int b = blockIdx.y;
  int idx = blockIdx.x * 256 + threadIdx.x;
  int i = idx / 192, j = idx % 192;
  if ((i >> 4) > (j >> 4)) G[b * 36864 + idx] = G[b * 36864 + j * 192 + i];
}

// ---------------- K2: energy -> softmax -> M(fp16 swizzled), c0 ----------------
__global__ __launch_bounds__(256) void k2_small(
    const float* __restrict__ G, const float* __restrict__ S,
    const float* __restrict__ Wq, const float* __restrict__ bq,
    const float* __restrict__ Wk, const float* __restrict__ bk,
    const float* __restrict__ Wv, const float* __restrict__ bv,
    _Float16* __restrict__ Mh, float* __restrict__ c0w) {
  const int b = blockIdx.y;
  const int cbase = blockIdx.x * 8;
  const int t = threadIdx.x;
  __shared__ float T1[192 * 9];
  __shared__ float el[64 * 8];
  __shared__ float sq[8];
  __shared__ float sk[64];
  const float* Gb = G + b * 36864;
  const float* Sb = S + b * 192;

  if (t < 8) {
    float a = 0.f;
    const float* wq = Wq + (cbase + t) * 192;
    for (int i = 0; i < 192; ++i) a = fmaf(wq[i], Sb[i], a);
    sq[t] = a;
  } else if (t < 72) {
    int d = t - 8;
    float a = 0.f;
    const float* wk = Wk + d * 192;
    for (int j = 0; j < 192; ++j) a = fmaf(wk[j], Sb[j], a);
    sk[d] = a;
  }
  for (int e = t; e < 1536; e += 256) {
    int j = e % 192, cp = e / 192;
    const float* wq = Wq + (cbase + cp) * 192;
    float a = 0.f;
    for (int i = 0; i < 192; ++i) a = fmaf(wq[i], Gb[i * 192 + j], a);
    T1[j * 9 + cp] = a;
  }
  __syncthreads();
  for (int e = t; e < 512; e += 256) {
    int cp = e & 7, d = e >> 3;
    const float* wk = Wk + d * 192;
    float a = 0.f;
    for (int j = 0; j < 192; ++j) a = fmaf(T1[j * 9 + cp], wk[j], a);
    float bqc = bq[cbase + cp], bkd = bk[d];
    a += bqc * sk[d] + bkd * sq[cp] + 65536.0f * bqc * bkd;
    el[d * 8 + cp] = a * 0.125f;
  }
  __syncthreads();
  if (t < 8) {
    float mx = -3.0e38f;
    for (int d = 0; d < 64; ++d) mx = fmaxf(mx, el[d * 8 + t]);
    float sum = 0.f;
    for (int d = 0; d < 64; ++d) {
      float pv = expf(el[d * 8 + t] - mx);
      el[d * 8 + t] = pv;
      sum += pv;
    }
    float inv = 1.0f / sum;
    for (int d = 0; d < 64; ++d) el[d * 8 + t] *= inv;
  }
  __syncthreads();
  // M rows in fp16, swizzled exactly as K3's lds_m image: idx = c*192 + (i ^ ((c&7)<<3))
  for (int e = t; e < 1536; e += 256) {
    int i = e % 192, cp = e / 192;
    int c = cbase + cp;
    float a = 0.f;
    for (int d = 0; d < 64; ++d) a = fmaf(el[d * 8 + cp], Wv[d * 192 + i], a);
    Mh[(size_t)b * 12288 + c * 192 + (i ^ ((c & 7) << 3))] = (_Float16)a;
  }
  if (t < 8) {
    float a = 0.f;
    for (int d = 0; d < 64; ++d) a = fmaf(el[d * 8 + t], bv[d], a);
    c0w[b * 64 + cbase + t] = a;
  }
}

// ---------------- K3: out = M X + c0 (fp16 MFMA) ----------------
// grid (256, 4), block 256 (4 waves). Block: C[64 x 256n]; wave w: n-span w*64.
// X chunk [32 i][256 n] staged transposed into lds_x[n][32] fp16, swizzle i^=(n&3)<<3.
// M staged once (linear copy of pre-swizzled fp16 image). acc[4][4] = 64 VGPR.
__global__ __launch_bounds__(256, 3) void k3_out(
    const float* __restrict__ rgb, const float* __restrict__ hsv, const float* __restrict__ lab,
    const _Float16* __restrict__ Mh, const float* __restrict__ c0w, float* __restrict__ out) {
  __shared__ alignas(16) _Float16 lds_m[12288];
  __shared__ alignas(16) _Float16 lds_x[8192];
  __shared__ float c0l[64];
  const int t = threadIdx.x;
  const int lane = t & 63;
  const int w = t >> 6;
  const int b = blockIdx.y;
  const int nblk = blockIdx.x * 256;

  {  // stage M (24576 B) as 16B copies + c0
    const float4* msrc = (const float4*)(Mh + (size_t)b * 12288);
    float4* mdst = (float4*)lds_m;
#pragma unroll
    for (int k = 0; k < 6; ++k) mdst[t + 256 * k] = msrc[t + 256 * k];
    if (t < 64) c0l[t] = c0w[b * 64 + t];
  }

  const int xi = t & 31;   // i within chunk
  const int ng = t >> 5;   // 0..7: n-group of 32
  const float* srcs[3] = {rgb, hsv, lab};

  f32x4_t acc[4][4];
  const f32x4_t zero4 = {0.0f, 0.0f, 0.0f, 0.0f};
#pragma unroll
  for (int i = 0; i < 4; ++i)
#pragma unroll
    for (int j = 0; j < 4; ++j) acc[i][j] = zero4;

  float4 xr[8];
  auto xload = [&](int kc) {
    int ig = kc * 32 + xi;
    const float* p = srcs[ig >> 6] + (size_t)(b * 64 + (ig & 63)) * NPIX + nblk + ng * 32;
#pragma unroll
    for (int f = 0; f < 8; ++f) xr[f] = *(const float4*)(p + f * 4);
  };
  auto xwrite = [&]() {
#pragma unroll
    for (int f = 0; f < 8; ++f) {
      int n = ng * 32 + f * 4;
      lds_x[(n + 0) * 32 + (xi ^ 0)]  = (_Float16)xr[f].x;
      lds_x[(n + 1) * 32 + (xi ^ 8)]  = (_Float16)xr[f].y;
      lds_x[(n + 2) * 32 + (xi ^ 16)] = (_Float16)xr[f].z;
      lds_x[(n + 3) * 32 + (xi ^ 24)] = (_Float16)xr[f].w;
    }
  };

  const int g = lane >> 4;     // 0..3
  const int l15 = lane & 15;

  xload(0);
  for (int kc = 0; kc < 6; ++kc) {
    xwrite();
    __syncthreads();
    if (kc + 1 < 6) xload(kc + 1);
    half8_t fx[4], fm[4];
#pragma unroll
    for (int nt = 0; nt < 4; ++nt) {
      int n = w * 64 + nt * 16 + l15;
      fx[nt] = *(const half8_t*)(lds_x + n * 32 + ((8 * g) ^ ((n & 3) << 3)));
    }
#pragma unroll
    for (int ct = 0; ct < 4; ++ct) {
      int c = ct * 16 + l15;
      fm[ct] = *(const half8_t*)(lds_m + c * 192 + ((kc * 32 + 8 * g) ^ ((c & 7) << 3)));
    }
#pragma unroll
    for (int nt = 0; nt < 4; ++nt)
#pragma unroll
      for (int ct = 0; ct < 4; ++ct)
        acc[nt][ct] = __builtin_amdgcn_mfma_f32_16x16x32_f16(fx[nt], fm[ct], acc[nt][ct], 0, 0, 0);
    __syncthreads();
  }

  // epilogue: C-row (n) = 4*g + r from first operand, C-col (c) = l15 from second
#pragma unroll
  for (int ct = 0; ct < 4; ++ct) {
    int c = ct * 16 + l15;
    float c0v = c0l[c];
#pragma unroll
    for (int nt = 0; nt < 4; ++nt) {
      int n = nblk + w * 64 + nt * 16 + 4 * g;
      float4 o;
      o.x = acc[nt][ct][0] + c0v;
      o.y = acc[nt][ct][1] + c0v;
      o.z = acc[nt][ct][2] + c0v;
      o.w = acc[nt][ct][3] + c0v;
      *(float4*)(out + (size_t)(b * 64 + c) * NPIX + n) = o;
    }
  }
}

extern "C" void kernel_launch(void* const* d_in, const int* in_sizes, int n_in,
                              void* d_out, int out_size, void* d_ws, size_t ws_size,
                              hipStream_t stream) {
  const float* rgb = (const float*)d_in[0];
  const float* hsv = (const float*)d_in[1];
  const float* lab = (const float*)d_in[2];
  const float* Wq = (const float*)d_in[3];
  const float* bq = (const float*)d_in[4];
  const float* Wk = (const float*)d_in[5];
  const float* bk = (const float*)d_in[6];
  const float* Wv = (const float*)d_in[7];
  const float* bv = (const float*)d_in[8];
  float* out = (float*)d_out;
  float* ws = (float*)d_ws;

  float* G = ws;                            // 147456 f32
  float* S = ws + 147456;                   // 768
  _Float16* Mh = (_Float16*)(ws + 148224);  // 49152 halves = 24576 f32 slots
  float* c0w = ws + 172800;                 // 256
  float* part = ws + 173056;                // 4*128*PSZ f32 = 41.3 MB
  const size_t need1 = (size_t)(173056 + 4 * 128 * PSZ) * 4;  // ~42 MB
  const int mode = ws_size >= need1 ? 1 : 0;

  if (!mode)
    k0_zero<<<dim3(579), dim3(256), 0, stream>>>(ws, 148224);  // zero G + S

  k1_gram<<<dim3(128, 4), dim3(512), 0, stream>>>(rgb, hsv, lab, G, S, part, mode);
  if (mode)
    k1r_reduce<<<dim3(315), dim3(256), 0, stream>>>(part, G, S);
  else
    k1m_mirror<<<dim3(144, 4), dim3(256), 0, stream>>>(G);
  k2_small<<<dim3(8, 4), dim3(256), 0, stream>>>(G, S, Wq, bq, Wk, bk, Wv, bv, Mh, c0w);
  k3_out<<<dim3(256, 4), dim3(256), 0, stream>>>(rgb, hsv, lab, Mh, c0w, out);
}